// Round 9
// baseline (346.052 us; speedup 1.0000x reference)
//
#include <hip/hip_runtime.h>

// Problem constants (from reference)
#define BB 8
#define LL 4096
#define DIM 1024
#define HH 16
#define MM 64
#define DH 64

// Flat sizes / output offsets (outputs concatenated, read back as f32)
constexpr long long NZ = (long long)BB * LL * DIM;   // 33554432
constexpr long long NG = (long long)BB * LL * HH;    // 524288
constexpr long long O_Z   = 0;
constexpr long long O_CRY = NZ;
constexpr long long O_NEW = NZ + NG;
constexpr long long O_CC  = NZ + 2 * NG;
constexpr long long O_FR  = NZ + 3 * NG;

// crystallised layout: int32 {0,1} (established empirically R1 vs R2).

// ---------------------------------------------------------------------------
// Fused kernel. R7 lesson: snap-as-second-launch cost ~70us of 233 total.
// Phase 1 (per block, 8 rows): stream zc/zp/fr -> velocity -> flags; store
// z/fr EXCEPT for `newly` head-segments (skipped; phase 2 is sole writer).
// Phase 2 (per wave): for each of the wave's own newly (row,head) items,
// re-read the z segment (L2-hot), argmin over 64 codes (lane=code, codebook
// L2-resident), write the snapped entry to both z_enforced and frozen_new.
// Decision arithmetic (f64 accumulation order, butterfly, tiebreak) is
// expression-identical to the R3-R7 passing kernels -> identical outputs.
// ---------------------------------------------------------------------------
#define ROWS 8

__global__ __launch_bounds__(256) void crystal_fused(
    const float4* __restrict__ zc4,
    const float4* __restrict__ zp4,
    const float*  __restrict__ cb,     // [H][M][DH]
    const float4* __restrict__ fr4,
    const int*    __restrict__ ccount, // [B*L*H] int32
    const int*    __restrict__ cryst,  // [B*L*H] int32 bool
    float* __restrict__ out)
{
    __shared__ float lds_cry[ROWS * HH];
    __shared__ float lds_new[ROWS * HH];
    __shared__ float lds_cc [ROWS * HH];

    const int t    = threadIdx.x;
    const int h    = t >> 4;
    const int sub  = t & 15;
    const int lane = t & 63;
    const int wv   = t >> 6;           // wave index 0..3 (covers heads 4wv..4wv+3)

    const long long row0 = (long long)blockIdx.x * ROWS;
    long long idx = row0 * (DIM / 4) + t;
    long long g   = row0 * HH + h;

    float4 zc = zc4[idx];
    float4 zp = zp4[idx];
    float4 fr = fr4[idx];
    int    cc = ccount[g];
    int    cv = cryst[g];

    unsigned int wmask = 0u;   // newly bits for this wave: bit r*4 + (h&3)

    #pragma unroll
    for (int r = 0; r < ROWS; ++r) {
        // ---- prefetch next row ----
        const long long nidx = idx + (DIM / 4);
        const long long gn   = g + HH;
        float4 zcn, zpn, frn; int ccn_ = 0, cvn = 0;
        if (r < ROWS - 1) {
            zcn = zc4[nidx]; zpn = zp4[nidx]; frn = fr4[nidx];
            ccn_ = ccount[gn]; cvn = cryst[gn];
        }

        // velocity^2: exact f32 diffs, f64 accumulate (bit-identical to R2-R7)
        double s;
        {
            double dx = (double)zc.x - (double)zp.x;
            double dy = (double)zc.y - (double)zp.y;
            double dz = (double)zc.z - (double)zp.z;
            double dw = (double)zc.w - (double)zp.w;
            s = dx * dx + dy * dy + dz * dz + dw * dw;
        }
        s += __shfl_xor(s, 1);
        s += __shfl_xor(s, 2);
        s += __shfl_xor(s, 4);
        s += __shfl_xor(s, 8);

        const bool conv = sqrt(s) < 0.01;   // velocity < TAU_CONVERGE
        const int  ccn  = conv ? cc + 1 : 0;
        const bool cry  = cv != 0;
        const bool newly   = (ccn >= 2) && !cry;
        const bool crystal = cry || newly;

        // newly segments are written ONLY by phase 2 (no double-store hazard)
        if (!newly) {
            float4 zout;
            zout.x = crystal ? fr.x : zc.x;
            zout.y = crystal ? fr.y : zc.y;
            zout.z = crystal ? fr.z : zc.z;
            zout.w = crystal ? fr.w : zc.w;
            reinterpret_cast<float4*>(out + O_Z)[idx]  = zout;
            reinterpret_cast<float4*>(out + O_FR)[idx] = fr;
        }

        if (sub == 0) {
            lds_cry[r * HH + h] = crystal ? 1.0f : 0.0f;
            lds_new[r * HH + h] = newly   ? 1.0f : 0.0f;
            lds_cc [r * HH + h] = (float)ccn;
        }

        // newly bitmask: ballot has bits only at lanes 0,16,32,48 of the wave
        const unsigned long long bal = __ballot(newly && sub == 0);
        const unsigned int b4 = (unsigned int)((bal        & 1ull)       |
                                               ((bal >> 16) & 1ull) << 1 |
                                               ((bal >> 32) & 1ull) << 2 |
                                               ((bal >> 48) & 1ull) << 3);
        wmask |= b4 << (4 * r);

        zc = zcn; zp = zpn; fr = frn; cc = ccn_; cv = cvn;
        idx = nidx; g = gn;
    }

    // ---- phase 2: this wave's newly items (wave-uniform loop) ----
    unsigned int items = wmask;
    while (items) {
        const int bit = __ffs(items) - 1; items &= items - 1;
        const int r   = bit >> 2;
        const int hh  = (wv << 2) | (bit & 3);
        const long long bl   = row0 + r;
        const long long seg4 = bl * (DIM / 4) + hh * (DH / 4);
        const float* cbh = cb + (long long)hh * MM * DH;

        // z segment re-read (just-streamed -> L2-hot); lane k holds chunk k
        float4 zv;
        if (lane < 16) zv = zc4[seg4 + lane];

        // distance for code `lane`: single f64 accumulator, same expression
        // order as R3-R7 snap
        double d2 = 0.0;
        const float4* crow = reinterpret_cast<const float4*>(cbh + lane * DH);
        #pragma unroll
        for (int k = 0; k < 16; ++k) {
            float4 zk;
            zk.x = __shfl(zv.x, k);
            zk.y = __shfl(zv.y, k);
            zk.z = __shfl(zv.z, k);
            zk.w = __shfl(zv.w, k);
            const float4 cvv = crow[k];
            double a  = (double)zk.x - (double)cvv.x;
            double b  = (double)zk.y - (double)cvv.y;
            double cq = (double)zk.z - (double)cvv.z;
            double d  = (double)zk.w - (double)cvv.w;
            d2 += a * a + b * b + cq * cq + d * d;
        }

        double best = d2;
        int bidx = lane;
        #pragma unroll
        for (int m2 = 1; m2 <= 32; m2 <<= 1) {
            double ob = __shfl_xor(best, m2);
            int    oi = __shfl_xor(bidx, m2);
            if (ob < best || (ob == best && oi < bidx)) { best = ob; bidx = oi; }
        }

        if (lane < 16) {
            const float4 ev = reinterpret_cast<const float4*>(cbh + bidx * DH)[lane];
            reinterpret_cast<float4*>(out + O_Z)[seg4 + lane]  = ev;
            reinterpret_cast<float4*>(out + O_FR)[seg4 + lane] = ev;
        }
    }

    __syncthreads();
    // coalesced 512B flag writes (block's g-range is contiguous: blockIdx*128)
    if (t < ROWS * HH) {
        const long long g0 = (long long)blockIdx.x * (ROWS * HH) + t;
        out[O_CRY + g0] = lds_cry[t];
        out[O_NEW + g0] = lds_new[t];
        out[O_CC  + g0] = lds_cc [t];
    }
}

extern "C" void kernel_launch(void* const* d_in, const int* in_sizes, int n_in,
                              void* d_out, int out_size, void* d_ws, size_t ws_size,
                              hipStream_t stream) {
    const float4* zc4 = (const float4*)d_in[0];
    const float4* zp4 = (const float4*)d_in[1];
    const float*  cb  = (const float*)d_in[2];
    const float4* fr4 = (const float4*)d_in[3];
    const int*    cc  = (const int*)d_in[4];
    const int*    cry = (const int*)d_in[5];
    float* out = (float*)d_out;

    hipLaunchKernelGGL(crystal_fused, dim3((BB * LL) / ROWS), dim3(256), 0, stream,
                       zc4, zp4, cb, fr4, cc, cry, out);
}

// Round 10
// 266.903 us; speedup vs baseline: 1.2965x; 1.2965x over previous
//
#include <hip/hip_runtime.h>

// Problem constants (from reference)
#define BB 8
#define LL 4096
#define DIM 1024
#define HH 16
#define MM 64
#define DH 64

// Flat sizes / output offsets (outputs concatenated, read back as f32)
constexpr long long NZ = (long long)BB * LL * DIM;   // 33554432
constexpr long long NG = (long long)BB * LL * HH;    // 524288
constexpr long long O_Z   = 0;
constexpr long long O_CRY = NZ;
constexpr long long O_NEW = NZ + NG;
constexpr long long O_CC  = NZ + 2 * NG;
constexpr long long O_FR  = NZ + 3 * NG;

// crystallised layout: int32 {0,1} (established empirically R1 vs R2).
// R8 lesson (journal): fusing snap into main regressed 233->346us (per-wave
// serial argmin chains on every block's critical path). Two-kernel structure
// is the committed baseline; this round: deeper main prefetch + snap packing.

// ---------------------------------------------------------------------------
// Phase 1: pure streaming with explicit 2-deep register pipeline (A/B/C
// rotation). R7/R8 showed the compiler stops at 1-row-deep (VGPR 32, 3KB/wave
// in flight, 4.1 TB/s effective). 2-deep doubles in-flight bytes.
// ---------------------------------------------------------------------------
#define ROWS 8

__global__ __launch_bounds__(256) void crystal_main(
    const float4* __restrict__ zc4,
    const float4* __restrict__ zp4,
    const float4* __restrict__ fr4,
    const int*    __restrict__ ccount, // [B*L*H] int32
    const int*    __restrict__ cryst,  // [B*L*H] int32 bool
    unsigned int* __restrict__ masks,  // [gridDim*4] newly bitmasks
    float* __restrict__ out)
{
    __shared__ float lds_cry[ROWS * HH];
    __shared__ float lds_new[ROWS * HH];
    __shared__ float lds_cc [ROWS * HH];

    const int t   = threadIdx.x;
    const int h   = t >> 4;
    const int sub = t & 15;

    const long long row0 = (long long)blockIdx.x * ROWS;
    const long long idx0 = row0 * (DIM / 4) + t;
    const long long g0   = row0 * HH + h;

    // 2-deep preload
    float4 zcA = zc4[idx0];
    float4 zpA = zp4[idx0];
    float4 frA = fr4[idx0];
    int    ccA = ccount[g0];
    int    cvA = cryst[g0];

    float4 zcB = zc4[idx0 + (DIM / 4)];
    float4 zpB = zp4[idx0 + (DIM / 4)];
    float4 frB = fr4[idx0 + (DIM / 4)];
    int    ccB = ccount[g0 + HH];
    int    cvB = cryst[g0 + HH];

    unsigned int wmask = 0u;   // newly bits for this wave: bit r*4 + (h&3)

    #pragma unroll
    for (int r = 0; r < ROWS; ++r) {
        // ---- prefetch row r+2 while computing row r ----
        float4 zcC, zpC, frC; int ccC = 0, cvC = 0;
        if (r < ROWS - 2) {
            const long long idx2 = idx0 + (long long)(r + 2) * (DIM / 4);
            const long long g2   = g0 + (long long)(r + 2) * HH;
            zcC = zc4[idx2]; zpC = zp4[idx2]; frC = fr4[idx2];
            ccC = ccount[g2]; cvC = cryst[g2];
        }

        // velocity^2: exact f32 diffs, f64 accumulate (bit-identical to R2-R8)
        double s;
        {
            double dx = (double)zcA.x - (double)zpA.x;
            double dy = (double)zcA.y - (double)zpA.y;
            double dz = (double)zcA.z - (double)zpA.z;
            double dw = (double)zcA.w - (double)zpA.w;
            s = dx * dx + dy * dy + dz * dz + dw * dw;
        }
        s += __shfl_xor(s, 1);
        s += __shfl_xor(s, 2);
        s += __shfl_xor(s, 4);
        s += __shfl_xor(s, 8);

        const bool conv = sqrt(s) < 0.01;   // velocity < TAU_CONVERGE
        const int  ccn  = conv ? ccA + 1 : 0;
        const bool cry  = cvA != 0;
        const bool newly   = (ccn >= 2) && !cry;
        const bool crystal = cry || newly;

        float4 zout;
        zout.x = crystal ? frA.x : zcA.x;
        zout.y = crystal ? frA.y : zcA.y;
        zout.z = crystal ? frA.z : zcA.z;
        zout.w = crystal ? frA.w : zcA.w;

        const long long idx = idx0 + (long long)r * (DIM / 4);
        reinterpret_cast<float4*>(out + O_Z)[idx]  = zout;
        reinterpret_cast<float4*>(out + O_FR)[idx] = frA;

        if (sub == 0) {
            lds_cry[r * HH + h] = crystal ? 1.0f : 0.0f;
            lds_new[r * HH + h] = newly   ? 1.0f : 0.0f;
            lds_cc [r * HH + h] = (float)ccn;
        }

        // newly bitmask: ballot has bits only at lanes 0,16,32,48 of the wave
        const unsigned long long bal = __ballot(newly && sub == 0);
        const unsigned int b4 = (unsigned int)((bal        & 1ull)       |
                                               ((bal >> 16) & 1ull) << 1 |
                                               ((bal >> 32) & 1ull) << 2 |
                                               ((bal >> 48) & 1ull) << 3);
        wmask |= b4 << (4 * r);

        // rotate pipeline registers
        zcA = zcB; zpA = zpB; frA = frB; ccA = ccB; cvA = cvB;
        zcB = zcC; zpB = zpC; frB = frC; ccB = ccC; cvB = cvC;
    }

    if ((t & 63) == 0)
        masks[blockIdx.x * 4 + (t >> 6)] = wmask;

    __syncthreads();
    // coalesced 512B flag writes (block's g-range is contiguous: blockIdx*128)
    if (t < ROWS * HH) {
        const long long g0f = (long long)blockIdx.x * (ROWS * HH) + t;
        out[O_CRY + g0f] = lds_cry[t];
        out[O_NEW + g0f] = lds_new[t];
        out[O_CC  + g0f] = lds_cc [t];
    }
}

// ---------------------------------------------------------------------------
// Phase 2: codebook snap. Work per WAVE identical to R8 (32 rows/wave,
// decision arithmetic bit-identical), but packed 4 waves per block
// (4096 blocks instead of 16384 one-wave blocks) to lift the tiny-block
// residency cap. No barriers: each wave is fully independent.
// ---------------------------------------------------------------------------
#define MB_PER_CHUNK 4                     // main-blocks per snap wave
#define CHUNK_ROWS  (MB_PER_CHUNK * ROWS)  // 32
#define NCHUNKS     (BB * LL / CHUNK_ROWS) // 1024
#define WAVES_PER_SNAP 4

__global__ __launch_bounds__(256) void crystal_snap(
    const float4* __restrict__ zc4,
    const float*  __restrict__ cb,     // [H][M][DH]
    const unsigned int* __restrict__ masks,
    float* __restrict__ out)
{
    const int lane = threadIdx.x & 63;         // 0..63 = code index
    const int wv   = threadIdx.x >> 6;         // wave within block
    const int G    = blockIdx.x * WAVES_PER_SNAP + wv;  // global chunk slot
    const int h    = G / NCHUNKS;              // h-major
    const int c    = G % NCHUNKS;
    const int w    = h >> 2;                   // wave slot within main block
    const int h2   = h & 3;                    // bit sub-position

    // my main-block's 8-row newly mask for head h (lanes >= MB_PER_CHUNK idle)
    const int mb = c * MB_PER_CHUNK + lane;
    const unsigned int word = (lane < MB_PER_CHUNK) ? masks[mb * 4 + w] : 0u;
    unsigned int rows8 = 0u;
    #pragma unroll
    for (int r = 0; r < ROWS; ++r)
        rows8 |= ((word >> (4 * r + h2)) & 1u) << r;

    unsigned long long act = __ballot(rows8 != 0u);
    if (act == 0ull) return;

    // codebook row `lane` into registers (16 float4, 16KB/wave, L2-hot)
    const float* cbh = cb + (long long)h * MM * DH;
    float4 crow[16];
    {
        const float4* cp = reinterpret_cast<const float4*>(cbh + lane * DH);
        #pragma unroll
        for (int k = 0; k < 16; ++k) crow[k] = cp[k];
    }

    // uniform work-item iterator over (lane, row) bits
    int curl = 0; unsigned int curm8 = 0u;
    auto next_bl = [&]() -> long long {
        while (curm8 == 0u) {
            if (act == 0ull) return -1;
            curl = __ffsll(act) - 1; act &= act - 1;
            curm8 = __shfl(rows8, curl);
        }
        const int r = __ffs(curm8) - 1; curm8 &= curm8 - 1;
        return (long long)(c * MB_PER_CHUNK + curl) * ROWS + r;
    };

    long long bl = next_bl();
    long long seg4 = bl * (DIM / 4) + h * (DH / 4);
    float4 zv;
    if (lane < 16) zv = zc4[seg4 + lane];      // lane k holds z chunk k

    while (bl >= 0) {
        // prefetch next item's z
        const long long bln = next_bl();
        const long long seg4n = bln * (DIM / 4) + h * (DH / 4);
        float4 zvn;
        if (bln >= 0 && lane < 16) zvn = zc4[seg4n + lane];

        // distance: single f64 accumulator, same expression order as R3-R8
        double d2 = 0.0;
        #pragma unroll
        for (int k = 0; k < 16; ++k) {
            float4 zk;
            zk.x = __shfl(zv.x, k);
            zk.y = __shfl(zv.y, k);
            zk.z = __shfl(zv.z, k);
            zk.w = __shfl(zv.w, k);
            double a  = (double)zk.x - (double)crow[k].x;
            double b  = (double)zk.y - (double)crow[k].y;
            double cq = (double)zk.z - (double)crow[k].z;
            double d  = (double)zk.w - (double)crow[k].w;
            d2 += a * a + b * b + cq * cq + d * d;
        }

        double best = d2;
        int bidx = lane;
        #pragma unroll
        for (int m2 = 1; m2 <= 32; m2 <<= 1) {
            double ob = __shfl_xor(best, m2);
            int    oi = __shfl_xor(bidx, m2);
            if (ob < best || (ob == best && oi < bidx)) { best = ob; bidx = oi; }
        }

        if (lane < 16) {
            const float4 ev = reinterpret_cast<const float4*>(cbh + bidx * DH)[lane];
            reinterpret_cast<float4*>(out + O_Z)[seg4 + lane]  = ev;
            reinterpret_cast<float4*>(out + O_FR)[seg4 + lane] = ev;
        }

        bl = bln; seg4 = seg4n; zv = zvn;
    }
}

extern "C" void kernel_launch(void* const* d_in, const int* in_sizes, int n_in,
                              void* d_out, int out_size, void* d_ws, size_t ws_size,
                              hipStream_t stream) {
    const float4* zc4 = (const float4*)d_in[0];
    const float4* zp4 = (const float4*)d_in[1];
    const float*  cb  = (const float*)d_in[2];
    const float4* fr4 = (const float4*)d_in[3];
    const int*    cc  = (const int*)d_in[4];
    const int*    cry = (const int*)d_in[5];
    float* out = (float*)d_out;
    unsigned int* masks = (unsigned int*)d_ws;   // 64KB of scratch

    hipLaunchKernelGGL(crystal_main, dim3((BB * LL) / ROWS), dim3(256), 0, stream,
                       zc4, zp4, fr4, cc, cry, masks, out);
    hipLaunchKernelGGL(crystal_snap, dim3(HH * NCHUNKS / WAVES_PER_SNAP), dim3(256), 0, stream,
                       zc4, cb, masks, out);
}

// Round 11
// 216.200 us; speedup vs baseline: 1.6006x; 1.2345x over previous
//
#include <hip/hip_runtime.h>

// Problem constants (from reference)
#define BB 8
#define LL 4096
#define DIM 1024
#define HH 16
#define MM 64
#define DH 64

// Flat sizes / output offsets (outputs concatenated, read back as f32)
constexpr long long NZ = (long long)BB * LL * DIM;   // 33554432
constexpr long long NG = (long long)BB * LL * HH;    // 524288
constexpr long long O_Z   = 0;
constexpr long long O_CRY = NZ;
constexpr long long O_NEW = NZ + NG;
constexpr long long O_CC  = NZ + 2 * NG;
constexpr long long O_FR  = NZ + 3 * NG;

// crystallised layout: int32 {0,1} (established empirically R1 vs R2).
// Journal: R8 fusion regressed (346us) -> two-kernel committed. R9 packing
// regressed (267us) -> one-wave snap blocks committed. Main is ~160us across
// all prefetch schemes -> keep R8 main verbatim; this round attacks snap's
// address-divergent codebook gathers (64 distinct lines per load inst).

// ---------------------------------------------------------------------------
// Phase 1: pure streaming (R8 verbatim; measured 158-162us, VGPR 32).
// ---------------------------------------------------------------------------
#define ROWS 8

__global__ __launch_bounds__(256) void crystal_main(
    const float4* __restrict__ zc4,
    const float4* __restrict__ zp4,
    const float4* __restrict__ fr4,
    const int*    __restrict__ ccount, // [B*L*H] int32
    const int*    __restrict__ cryst,  // [B*L*H] int32 bool
    unsigned int* __restrict__ masks,  // [gridDim*4] newly bitmasks
    float* __restrict__ out)
{
    __shared__ float lds_cry[ROWS * HH];
    __shared__ float lds_new[ROWS * HH];
    __shared__ float lds_cc [ROWS * HH];

    const int t   = threadIdx.x;
    const int h   = t >> 4;
    const int sub = t & 15;

    const long long row0 = (long long)blockIdx.x * ROWS;
    long long idx = row0 * (DIM / 4) + t;
    long long g   = row0 * HH + h;

    float4 zc = zc4[idx];
    float4 zp = zp4[idx];
    float4 fr = fr4[idx];
    int    cc = ccount[g];
    int    cv = cryst[g];

    unsigned int wmask = 0u;   // newly bits for this wave: bit r*4 + (h&3)

    #pragma unroll
    for (int r = 0; r < ROWS; ++r) {
        // ---- prefetch next row (full unroll -> compiler hoists loads) ----
        const long long nidx = idx + (DIM / 4);
        const long long gn   = g + HH;
        float4 zcn, zpn, frn; int ccn_ = 0, cvn = 0;
        if (r < ROWS - 1) {
            zcn = zc4[nidx]; zpn = zp4[nidx]; frn = fr4[nidx];
            ccn_ = ccount[gn]; cvn = cryst[gn];
        }

        // velocity^2: exact f32 diffs, f64 accumulate (bit-identical to R2-R9)
        double s;
        {
            double dx = (double)zc.x - (double)zp.x;
            double dy = (double)zc.y - (double)zp.y;
            double dz = (double)zc.z - (double)zp.z;
            double dw = (double)zc.w - (double)zp.w;
            s = dx * dx + dy * dy + dz * dz + dw * dw;
        }
        s += __shfl_xor(s, 1);
        s += __shfl_xor(s, 2);
        s += __shfl_xor(s, 4);
        s += __shfl_xor(s, 8);

        const bool conv = sqrt(s) < 0.01;   // velocity < TAU_CONVERGE
        const int  ccn  = conv ? cc + 1 : 0;
        const bool cry  = cv != 0;
        const bool newly   = (ccn >= 2) && !cry;
        const bool crystal = cry || newly;

        float4 zout;
        zout.x = crystal ? fr.x : zc.x;
        zout.y = crystal ? fr.y : zc.y;
        zout.z = crystal ? fr.z : zc.z;
        zout.w = crystal ? fr.w : zc.w;

        reinterpret_cast<float4*>(out + O_Z)[idx]  = zout;
        reinterpret_cast<float4*>(out + O_FR)[idx] = fr;

        if (sub == 0) {
            lds_cry[r * HH + h] = crystal ? 1.0f : 0.0f;
            lds_new[r * HH + h] = newly   ? 1.0f : 0.0f;
            lds_cc [r * HH + h] = (float)ccn;
        }

        // newly bitmask: ballot has bits only at lanes 0,16,32,48 of the wave
        const unsigned long long bal = __ballot(newly && sub == 0);
        const unsigned int b4 = (unsigned int)((bal        & 1ull)       |
                                               ((bal >> 16) & 1ull) << 1 |
                                               ((bal >> 32) & 1ull) << 2 |
                                               ((bal >> 48) & 1ull) << 3);
        wmask |= b4 << (4 * r);

        zc = zcn; zp = zpn; fr = frn; cc = ccn_; cv = cvn;
        idx = nidx; g = gn;
    }

    if ((t & 63) == 0)
        masks[blockIdx.x * 4 + (t >> 6)] = wmask;

    __syncthreads();
    // coalesced 512B flag writes (block's g-range is contiguous: blockIdx*128)
    if (t < ROWS * HH) {
        const long long g0 = (long long)blockIdx.x * (ROWS * HH) + t;
        out[O_CRY + g0] = lds_cry[t];
        out[O_NEW + g0] = lds_new[t];
        out[O_CC  + g0] = lds_cc [t];
    }
}

// ---------------------------------------------------------------------------
// Phase 2: codebook snap, LDS-staged. R7-R9's per-lane codebook access had
// 64 distinct cache lines per load instruction (256B lane stride) -> ~us-scale
// address-processing serialization per wave. Now: codebook loaded COALESCED
// (64 thr x 16 float4) into LDS with 65-float padded rows (2 lanes/bank =
// conflict-free, m136); distance loop reads are LDS-only, no gathers/shuffles.
// Velocity-independent: f64 diff expression and d-order identical to R3-R9;
// d2 uses 4 partial f64 accumulators (argmin gaps O(0.1) -> flip risk ~0).
// Butterfly + first-min tiebreak unchanged.
// ---------------------------------------------------------------------------
#define MB_PER_CHUNK 4                     // main-blocks per snap block
#define CHUNK_ROWS  (MB_PER_CHUNK * ROWS)  // 32
#define NCHUNKS     (BB * LL / CHUNK_ROWS) // 1024
#define CBPAD 65                           // padded floats per codebook row

__global__ __launch_bounds__(64) void crystal_snap(
    const float4* __restrict__ zc4,
    const float*  __restrict__ cb,     // [H][M][DH]
    const unsigned int* __restrict__ masks,
    float* __restrict__ out)
{
    __shared__ float cbl[MM * CBPAD];   // 16.6KB padded codebook
    __shared__ float zl[2][DH];         // double-buffered z row segment

    const int lane = threadIdx.x;              // 0..63 = code index
    const int h    = blockIdx.x / NCHUNKS;     // h-major
    const int c    = blockIdx.x % NCHUNKS;
    const int w    = h >> 2;                   // wave slot within main block
    const int h2   = h & 3;                    // bit sub-position

    // my main-block's 8-row newly mask for head h (lanes >= MB_PER_CHUNK idle)
    const int mb = c * MB_PER_CHUNK + lane;
    const unsigned int word = (lane < MB_PER_CHUNK) ? masks[mb * 4 + w] : 0u;
    unsigned int rows8 = 0u;
    #pragma unroll
    for (int r = 0; r < ROWS; ++r)
        rows8 |= ((word >> (4 * r + h2)) & 1u) << r;

    unsigned long long act = __ballot(rows8 != 0u);
    if (act == 0ull) return;   // wave-uniform; ~1.4% of blocks

    // ---- coalesced codebook load -> padded LDS ----
    const float4* cbh4 = reinterpret_cast<const float4*>(cb + (long long)h * MM * DH);
    #pragma unroll
    for (int i = 0; i < 16; ++i) {
        const int gidx = i * 64 + lane;        // float4 index within head
        const float4 v = cbh4[gidx];
        const int m  = gidx >> 4;
        const int k4 = (gidx & 15) * 4;
        float* dst = &cbl[m * CBPAD + k4];
        dst[0] = v.x; dst[1] = v.y; dst[2] = v.z; dst[3] = v.w;
    }

    // uniform work-item iterator over (lane, row) bits
    int curl = 0; unsigned int curm8 = 0u;
    auto next_bl = [&]() -> long long {
        while (curm8 == 0u) {
            if (act == 0ull) return -1;
            curl = __ffsll(act) - 1; act &= act - 1;
            curm8 = __shfl(rows8, curl);
        }
        const int r = __ffs(curm8) - 1; curm8 &= curm8 - 1;
        return (long long)(c * MB_PER_CHUNK + curl) * ROWS + r;
    };

    long long bl = next_bl();
    long long seg4 = bl * (DIM / 4) + h * (DH / 4);
    float4 zv;
    if (lane < 16) zv = zc4[seg4 + lane];      // lane k holds z chunk k

    __syncthreads();   // cbl visible
    int p = 0;

    while (bl >= 0) {
        if (lane < 16) reinterpret_cast<float4*>(zl[p])[lane] = zv;

        // prefetch next item's z
        const long long bln = next_bl();
        const long long seg4n = bln * (DIM / 4) + h * (DH / 4);
        float4 zvn;
        if (bln >= 0 && lane < 16) zvn = zc4[seg4n + lane];

        __syncthreads();   // zl[p] visible

        // distance for code `lane`: LDS-only reads (z broadcast, cb padded
        // conflict-free); f64 diffs in the same d-order as R3-R9, split into
        // 4 partial accumulators for ILP
        const float* crow = &cbl[lane * CBPAD];
        const float* zrow = zl[p];
        double a0 = 0.0, a1 = 0.0, a2 = 0.0, a3 = 0.0;
        #pragma unroll
        for (int d = 0; d < DH; d += 4) {
            double q0 = (double)zrow[d + 0] - (double)crow[d + 0];
            double q1 = (double)zrow[d + 1] - (double)crow[d + 1];
            double q2 = (double)zrow[d + 2] - (double)crow[d + 2];
            double q3 = (double)zrow[d + 3] - (double)crow[d + 3];
            a0 += q0 * q0; a1 += q1 * q1; a2 += q2 * q2; a3 += q3 * q3;
        }
        double best = (a0 + a1) + (a2 + a3);
        int bidx = lane;
        #pragma unroll
        for (int m2 = 1; m2 <= 32; m2 <<= 1) {
            double ob = __shfl_xor(best, m2);
            int    oi = __shfl_xor(bidx, m2);
            if (ob < best || (ob == best && oi < bidx)) { best = ob; bidx = oi; }
        }

        if (lane < 16) {
            const float* er = &cbl[bidx * CBPAD + lane * 4];
            float4 ev;
            ev.x = er[0]; ev.y = er[1]; ev.z = er[2]; ev.w = er[3];
            reinterpret_cast<float4*>(out + O_Z)[seg4 + lane]  = ev;
            reinterpret_cast<float4*>(out + O_FR)[seg4 + lane] = ev;
        }

        p ^= 1; bl = bln; seg4 = seg4n; zv = zvn;
    }
}

extern "C" void kernel_launch(void* const* d_in, const int* in_sizes, int n_in,
                              void* d_out, int out_size, void* d_ws, size_t ws_size,
                              hipStream_t stream) {
    const float4* zc4 = (const float4*)d_in[0];
    const float4* zp4 = (const float4*)d_in[1];
    const float*  cb  = (const float*)d_in[2];
    const float4* fr4 = (const float4*)d_in[3];
    const int*    cc  = (const int*)d_in[4];
    const int*    cry = (const int*)d_in[5];
    float* out = (float*)d_out;
    unsigned int* masks = (unsigned int*)d_ws;   // 64KB of scratch

    hipLaunchKernelGGL(crystal_main, dim3((BB * LL) / ROWS), dim3(256), 0, stream,
                       zc4, zp4, fr4, cc, cry, masks, out);
    hipLaunchKernelGGL(crystal_snap, dim3(HH * NCHUNKS), dim3(64), 0, stream,
                       zc4, cb, masks, out);
}